// Round 2
// baseline (838.460 us; speedup 1.0000x reference)
//
#include <hip/hip_runtime.h>
#include <cstddef>

#define B_  64
#define D_  128
#define LC_ 1000
#define LQ_ 100
#define JP  128   // padded LQ

// ---------------- K0: transpose C (B,D,LC) -> Ct (B,LC,D) ----------------
__global__ __launch_bounds__(256) void k_transpose(const float* __restrict__ C,
                                                   float* __restrict__ Ct){
  __shared__ float t[32][33];
  int b  = blockIdx.z;
  int i0 = blockIdx.x * 32;
  int d0 = blockIdx.y * 32;
  int tx = threadIdx.x;          // 0..31
  int ty = threadIdx.y;          // 0..7
  const float* Cb  = C  + (size_t)b * D_ * LC_;
  float*       Ctb = Ct + (size_t)b * LC_ * D_;
#pragma unroll
  for(int k=0;k<4;k++){
    int d = d0 + ty + 8*k;
    int i = i0 + tx;
    t[ty+8*k][tx] = (i < LC_) ? Cb[(size_t)d*LC_ + i] : 0.f;
  }
  __syncthreads();
#pragma unroll
  for(int k=0;k<4;k++){
    int i = i0 + ty + 8*k;
    int d = d0 + tx;
    if(i < LC_) Ctb[(size_t)i*D_ + d] = t[tx][ty+8*k];
  }
}

// ---------------- K1: S[b,i,j] = sum_d (w1+w3*Ct)[i,d]*Q[d,j] + t2[i] ----------------
// block: 256 thr, tile 64 i x 128 j (padded), K=128 in 4 chunks of 32.
__global__ __launch_bounds__(256) void k_S(const float* __restrict__ Q,
                                           const float* __restrict__ W,
                                           const float* __restrict__ Ct,
                                           float* __restrict__ S){
  __shared__ float Qs[32][132];   // [d-chunk][j]
  __shared__ float Vs[64][33];    // [i_local][d-chunk]
  __shared__ float t2s[64];
  int b   = blockIdx.y;
  int i0  = blockIdx.x * 64;
  int tid = threadIdx.x;
  const float* Wb  = W  + (size_t)b * LC_ * 384;
  const float* Ctb = Ct + (size_t)b * LC_ * D_;
  const float* Qb  = Q  + (size_t)b * D_ * LQ_;

  // ---- t2 phase: t2[i] = sum_d w2[i,d]*Ct[i,d], 32-lane groups ----
  {
    int g = tid >> 5, l = tid & 31;
    for(int rep=0; rep<8; rep++){
      int il = rep*8 + g;
      int i  = i0 + il;
      float s = 0.f;
      if(i < LC_){
        const float* wrow  = Wb  + (size_t)i*384 + 128;
        const float* ctrow = Ctb + (size_t)i*D_;
#pragma unroll
        for(int k=0;k<4;k++){ int d = l + 32*k; s += wrow[d]*ctrow[d]; }
      }
#pragma unroll
      for(int m=16;m>0;m>>=1) s += __shfl_xor(s, m, 64);
      if(l==0) t2s[il] = s;
    }
  }

  int jt = tid & 15;   // j = jt*8 + jj
  int ti = tid >> 4;   // i_local = ti*4 + ii
  float acc[4][8] = {};

  for(int c=0;c<4;c++){
    int dc0 = c*32;
    __syncthreads();
    // stage Q chunk
    for(int idx=tid; idx<32*128; idx+=256){
      int dc = idx >> 7, j = idx & 127;
      Qs[dc][j] = (j < LQ_) ? Qb[(size_t)(dc0+dc)*LQ_ + j] : 0.f;
    }
    // stage V chunk: V = w1 + w3*Ct
    for(int idx=tid; idx<64*32; idx+=256){
      int il = idx >> 5, dc = idx & 31;
      int i = i0 + il;
      float v = 0.f;
      if(i < LC_){
        const float* wrow = Wb + (size_t)i*384;
        float ct = Ctb[(size_t)i*D_ + dc0+dc];
        v = wrow[dc0+dc] + wrow[256+dc0+dc]*ct;
      }
      Vs[il][dc] = v;
    }
    __syncthreads();
#pragma unroll 4
    for(int dc=0; dc<32; dc++){
      float v[4];
#pragma unroll
      for(int ii=0; ii<4; ii++) v[ii] = Vs[ti*4+ii][dc];
      float4 q0 = *(const float4*)&Qs[dc][jt*8];
      float4 q1 = *(const float4*)&Qs[dc][jt*8+4];
      float q[8] = {q0.x,q0.y,q0.z,q0.w,q1.x,q1.y,q1.z,q1.w};
#pragma unroll
      for(int ii=0; ii<4; ii++)
#pragma unroll
        for(int jj=0; jj<8; jj++) acc[ii][jj] += v[ii]*q[jj];
    }
  }
  // epilogue
  float* Sb = S + (size_t)b * LC_ * JP;
#pragma unroll
  for(int ii=0; ii<4; ii++){
    int il = ti*4+ii;
    int i  = i0 + il;
    if(i < LC_){
      float t2v = t2s[il];
      float4 o0, o1;
      o0.x=acc[ii][0]+t2v; o0.y=acc[ii][1]+t2v; o0.z=acc[ii][2]+t2v; o0.w=acc[ii][3]+t2v;
      o1.x=acc[ii][4]+t2v; o1.y=acc[ii][5]+t2v; o1.z=acc[ii][6]+t2v; o1.w=acc[ii][7]+t2v;
      *(float4*)&Sb[(size_t)i*JP + jt*8    ] = o0;
      *(float4*)&Sb[(size_t)i*JP + jt*8 + 4] = o1;
    }
  }
}

// ---------------- K2: column stats over i (softmax axis=1) ----------------
__global__ __launch_bounds__(256) void k_colstats(const float* __restrict__ S,
                                                  float* __restrict__ cm,
                                                  float* __restrict__ cs){
  __shared__ float ms[2][128], ss[2][128];
  int b = blockIdx.x;
  int j = threadIdx.x & 127, h = threadIdx.x >> 7;
  const float* Sb = S + (size_t)b * LC_ * JP;
  float m = -1e30f, s = 0.f;
  for(int i=h*500; i<h*500+500; i++){
    float x = Sb[(size_t)i*JP + j];
    if(x > m){ s = s*__expf(m-x) + 1.f; m = x; }
    else      s += __expf(x-m);
  }
  ms[h][j]=m; ss[h][j]=s;
  __syncthreads();
  if(h==0){
    float m1=ms[1][j], s1=ss[1][j];
    float mm = fmaxf(m,m1);
    cm[b*JP+j] = mm;
    cs[b*JP+j] = s*__expf(m-mm) + s1*__expf(m1-mm);
  }
}

// ---------------- K3: M[b,j,d] = sum_i softmax_col(S)[i,j]*Ct[i,d] (split-K, atomics) ----------------
#define KCH 250
__global__ __launch_bounds__(256) void k_M(const float* __restrict__ S,
                                           const float* __restrict__ Ct,
                                           const float* __restrict__ cm_,
                                           const float* __restrict__ cs_,
                                           float* __restrict__ M){
  __shared__ float Es[16][132];
  __shared__ float Cs[16][68];
  __shared__ float cml[128], icsl[128];
  int b   = blockIdx.x;
  int ic0 = blockIdx.y * KCH;
  int dh  = blockIdx.z;          // d half
  int tid = threadIdx.x;
  if(tid < 128){ cml[tid] = cm_[b*JP+tid]; icsl[tid] = 1.f/cs_[b*JP+tid]; }
  int jt = tid & 15, dt = tid >> 4;
  float acc[8][4] = {};
  const float* Sb  = S  + (size_t)b * LC_ * JP;
  const float* Ctb = Ct + (size_t)b * LC_ * D_ + dh*64;
  for(int s0=0; s0<KCH; s0+=16){
    int rem = KCH - s0;
    __syncthreads();
    for(int idx=tid; idx<16*128; idx+=256){
      int ii = idx >> 7, j = idx & 127;
      float e = 0.f;
      if(j < LQ_ && ii < rem){
        int i = ic0 + s0 + ii;
        e = __expf(Sb[(size_t)i*JP + j] - cml[j]);
      }
      Es[ii][j] = e;
    }
    for(int idx=tid; idx<16*64; idx+=256){
      int ii = idx >> 6, dl = idx & 63;
      float v = 0.f;
      if(ii < rem){ int i = ic0 + s0 + ii; v = Ctb[(size_t)i*D_ + dl]; }
      Cs[ii][dl] = v;
    }
    __syncthreads();
#pragma unroll 4
    for(int ii=0; ii<16; ii++){
      float4 e0 = *(const float4*)&Es[ii][jt*8];
      float4 e1 = *(const float4*)&Es[ii][jt*8+4];
      float e[8] = {e0.x,e0.y,e0.z,e0.w,e1.x,e1.y,e1.z,e1.w};
      float4 c4 = *(const float4*)&Cs[ii][dt*4];
      float cc[4] = {c4.x,c4.y,c4.z,c4.w};
#pragma unroll
      for(int jj=0; jj<8; jj++)
#pragma unroll
        for(int dd=0; dd<4; dd++) acc[jj][dd] += e[jj]*cc[dd];
    }
  }
  float* Mb = M + (size_t)b * JP * D_ + dh*64;
#pragma unroll
  for(int jj=0; jj<8; jj++){
    int j = jt*8+jj;
    float ics = icsl[j];
#pragma unroll
    for(int dd=0; dd<4; dd++)
      atomicAdd(&Mb[(size_t)j*D_ + dt*4+dd], acc[jj][dd]*ics);
  }
}

// ---------------- K4: row softmax + A=S1@Qt + Bm=S1@M + assemble output ----------------
// block 256, tile 64 i x 64 d (d-half), K=128 j
__global__ __launch_bounds__(256) void k_final(const float* __restrict__ S,
                                               const float* __restrict__ Q,
                                               const float* __restrict__ M,
                                               const float* __restrict__ C,
                                               float* __restrict__ out){
  __shared__ float S1s[64][132];
  __shared__ float Qs[128][68];   // [j][d_local]; reused as A_lds
  __shared__ float Ms[128][68];   // [j][d_local]; reused as Bm_lds
  int b   = blockIdx.z;
  int i0  = blockIdx.x * 64;
  int dh  = blockIdx.y;
  int tid = threadIdx.x;
  const float* Sb = S + (size_t)b * LC_ * JP;
  for(int idx=tid; idx<64*128; idx+=256){
    int il = idx >> 7, j = idx & 127;
    int i = i0 + il;
    S1s[il][j] = (i < LC_) ? Sb[(size_t)i*JP + j] : 0.f;
  }
  const float* Qb = Q + ((size_t)b*D_ + dh*64) * LQ_;
  for(int idx=tid; idx<64*128; idx+=256){
    int dl = idx >> 7, j = idx & 127;
    Qs[j][dl] = (j < LQ_) ? Qb[(size_t)dl*LQ_ + j] : 0.f;
  }
  const float* Mb = M + (size_t)b * JP * D_ + dh*64;
  for(int idx=tid; idx<128*64; idx+=256){
    int j = idx >> 6, dl = idx & 63;
    Ms[j][dl] = Mb[(size_t)j*D_ + dl];
  }
  __syncthreads();
  // in-LDS row softmax over j<100 (one wave per 16 rows; 2 elems/lane)
  {
    int w = tid >> 6, l = tid & 63;
    for(int r=0; r<16; r++){
      int il = w*16 + r;
      float x0 = (2*l   < LQ_) ? S1s[il][2*l  ] : -1e30f;
      float x1 = (2*l+1 < LQ_) ? S1s[il][2*l+1] : -1e30f;
      float m = fmaxf(x0,x1);
#pragma unroll
      for(int mm=32;mm>0;mm>>=1) m = fmaxf(m, __shfl_xor(m, mm, 64));
      float e0 = (2*l   < LQ_) ? __expf(x0-m) : 0.f;
      float e1 = (2*l+1 < LQ_) ? __expf(x1-m) : 0.f;
      float s = e0+e1;
#pragma unroll
      for(int mm=32;mm>0;mm>>=1) s += __shfl_xor(s, mm, 64);
      float inv = 1.f/s;
      S1s[il][2*l  ] = e0*inv;
      S1s[il][2*l+1] = e1*inv;
    }
  }
  __syncthreads();
  // dual GEMM: thread tile 4i x 4d (i strided by 16, d contiguous 4)
  int dt = tid & 15, it = tid >> 4;
  float A[4][4] = {}, Bm[4][4] = {};
  for(int j4=0; j4<128; j4+=4){
    float4 s1[4];
#pragma unroll
    for(int ii=0; ii<4; ii++) s1[ii] = *(const float4*)&S1s[it + 16*ii][j4];
    float4 qv[4], mv[4];
#pragma unroll
    for(int jj=0; jj<4; jj++){
      qv[jj] = *(const float4*)&Qs[j4+jj][dt*4];
      mv[jj] = *(const float4*)&Ms[j4+jj][dt*4];
    }
#pragma unroll
    for(int ii=0; ii<4; ii++){
      float sv[4] = {s1[ii].x, s1[ii].y, s1[ii].z, s1[ii].w};
#pragma unroll
      for(int jj=0; jj<4; jj++){
        A[ii][0]  += sv[jj]*qv[jj].x; A[ii][1]  += sv[jj]*qv[jj].y;
        A[ii][2]  += sv[jj]*qv[jj].z; A[ii][3]  += sv[jj]*qv[jj].w;
        Bm[ii][0] += sv[jj]*mv[jj].x; Bm[ii][1] += sv[jj]*mv[jj].y;
        Bm[ii][2] += sv[jj]*mv[jj].z; Bm[ii][3] += sv[jj]*mv[jj].w;
      }
    }
  }
  // epilogue: LDS round-trip for i-coalesced output writes
  __syncthreads();
#pragma unroll
  for(int ii=0; ii<4; ii++)
#pragma unroll
    for(int dd=0; dd<4; dd++){
      Qs[it + 16*ii][dt*4+dd] = A[ii][dd];
      Ms[it + 16*ii][dt*4+dd] = Bm[ii][dd];
    }
  __syncthreads();
  {
    int il2 = tid & 63, dg = tid >> 6;
    int i = i0 + il2;
    if(i < LC_){
      const float* Cb = C + ((size_t)b*D_ + dh*64) * LC_;
      float* ob = out + (size_t)b * 512 * LC_;
#pragma unroll
      for(int dd2=0; dd2<16; dd2++){
        int dl = dg*16 + dd2;
        float c  = Cb[(size_t)dl*LC_ + i];
        float a  = Qs[il2][dl];
        float bm = Ms[il2][dl];
        int d = dh*64 + dl;
        ob[(size_t)d*LC_ + i]        = c;
        ob[(size_t)(128+d)*LC_ + i]  = a;
        ob[(size_t)(256+d)*LC_ + i]  = c*a;
        ob[(size_t)(384+d)*LC_ + i]  = c*bm;
      }
    }
  }
}

extern "C" void kernel_launch(void* const* d_in, const int* in_sizes, int n_in,
                              void* d_out, int out_size, void* d_ws, size_t ws_size,
                              hipStream_t stream){
  const float* C = (const float*)d_in[0];
  const float* Q = (const float*)d_in[1];
  const float* W = (const float*)d_in[2];
  float* out = (float*)d_out;
  float* ws  = (float*)d_ws;
  // ws layout (floats): S 8.192M | Ct 8.192M | M 1.0486M | cm 8192 | cs 8192  => 69.8 MB
  float* S  = ws;
  float* Ct = ws + 8192000;
  float* M  = ws + 16384000;
  float* cm = ws + 17432576;
  float* cs = ws + 17440768;

  hipMemsetAsync(M, 0, (size_t)JP*D_*B_*sizeof(float), stream);
  k_transpose<<<dim3(32,4,64), dim3(32,8), 0, stream>>>(C, Ct);
  k_S<<<dim3(16,64), 256, 0, stream>>>(Q, W, Ct, S);
  k_colstats<<<64, 256, 0, stream>>>(S, cm, cs);
  k_M<<<dim3(64,4,2), 256, 0, stream>>>(S, Ct, cm, cs, M);
  k_final<<<dim3(16,2,64), 256, 0, stream>>>(S, Q, M, C, out);
}

// Round 3
// 621.105 us; speedup vs baseline: 1.3499x; 1.3499x over previous
//
#include <hip/hip_runtime.h>
#include <cstddef>

#define B_  64
#define D_  128
#define LC_ 1000
#define LQ_ 100
#define SP  104   // S row stride (padded LQ, mult of 8)
#define JP  128   // cm/cs stride

// ---------------- K0: transpose C (B,D,LC) -> Ct (B,LC,D) ----------------
__global__ __launch_bounds__(256) void k_transpose(const float* __restrict__ C,
                                                   float* __restrict__ Ct){
  __shared__ float t[32][33];
  int b  = blockIdx.z;
  int i0 = blockIdx.x * 32;
  int d0 = blockIdx.y * 32;
  int tx = threadIdx.x, ty = threadIdx.y;
  const float* Cb  = C  + (size_t)b * D_ * LC_;
  float*       Ctb = Ct + (size_t)b * LC_ * D_;
#pragma unroll
  for(int k=0;k<4;k++){
    int d = d0 + ty + 8*k;
    int i = i0 + tx;
    t[ty+8*k][tx] = (i < LC_) ? Cb[(size_t)d*LC_ + i] : 0.f;
  }
  __syncthreads();
#pragma unroll
  for(int k=0;k<4;k++){
    int i = i0 + ty + 8*k;
    int d = d0 + tx;
    if(i < LC_) Ctb[(size_t)i*D_ + d] = t[tx][ty+8*k];
  }
}

// ---------------- K0b: transpose Q (B,D,LQ) -> Qt (B,LQ,D) ----------------
__global__ __launch_bounds__(256) void k_transposeQ(const float* __restrict__ Q,
                                                    float* __restrict__ Qt){
  __shared__ float t[32][33];
  int b  = blockIdx.z;
  int j0 = blockIdx.x * 32;
  int d0 = blockIdx.y * 32;
  int tx = threadIdx.x, ty = threadIdx.y;
  const float* Qb  = Q  + (size_t)b * D_ * LQ_;
  float*       Qtb = Qt + (size_t)b * LQ_ * D_;
#pragma unroll
  for(int k=0;k<4;k++){
    int d = d0 + ty + 8*k;
    int j = j0 + tx;
    t[ty+8*k][tx] = (j < LQ_) ? Qb[(size_t)d*LQ_ + j] : 0.f;
  }
  __syncthreads();
#pragma unroll
  for(int k=0;k<4;k++){
    int j = j0 + ty + 8*k;
    int d = d0 + tx;
    if(j < LQ_) Qtb[(size_t)j*D_ + d] = t[tx][ty+8*k];
  }
}

// ---------------- K1: S[b,i,j] = sum_d (w1+w3*Ct)[i,d]*Q[d,j] + t2[i] ----------------
__global__ __launch_bounds__(256) void k_S(const float* __restrict__ Q,
                                           const float* __restrict__ W,
                                           const float* __restrict__ Ct,
                                           float* __restrict__ S){
  __shared__ float Qs[32][132];
  __shared__ float Vs[64][33];
  __shared__ float t2s[64];
  int b   = blockIdx.y;
  int i0  = blockIdx.x * 64;
  int tid = threadIdx.x;
  const float* Wb  = W  + (size_t)b * LC_ * 384;
  const float* Ctb = Ct + (size_t)b * LC_ * D_;
  const float* Qb  = Q  + (size_t)b * D_ * LQ_;

  // t2[i] = sum_d w2[i,d]*Ct[i,d]
  {
    int g = tid >> 5, l = tid & 31;
    for(int rep=0; rep<8; rep++){
      int il = rep*8 + g;
      int i  = i0 + il;
      float s = 0.f;
      if(i < LC_){
        const float* wrow  = Wb  + (size_t)i*384 + 128;
        const float* ctrow = Ctb + (size_t)i*D_;
#pragma unroll
        for(int k=0;k<4;k++){ int d = l + 32*k; s += wrow[d]*ctrow[d]; }
      }
#pragma unroll
      for(int m=16;m>0;m>>=1) s += __shfl_xor(s, m, 64);
      if(l==0) t2s[il] = s;
    }
  }

  int jt = tid & 15;
  int ti = tid >> 4;
  float acc[4][8] = {};

  for(int c=0;c<4;c++){
    int dc0 = c*32;
    __syncthreads();
    for(int idx=tid; idx<32*128; idx+=256){
      int dc = idx >> 7, j = idx & 127;
      Qs[dc][j] = (j < LQ_) ? Qb[(size_t)(dc0+dc)*LQ_ + j] : 0.f;
    }
    for(int idx=tid; idx<64*32; idx+=256){
      int il = idx >> 5, dc = idx & 31;
      int i = i0 + il;
      float v = 0.f;
      if(i < LC_){
        const float* wrow = Wb + (size_t)i*384;
        float ct = Ctb[(size_t)i*D_ + dc0+dc];
        v = wrow[dc0+dc] + wrow[256+dc0+dc]*ct;
      }
      Vs[il][dc] = v;
    }
    __syncthreads();
#pragma unroll 4
    for(int dc=0; dc<32; dc++){
      float v[4];
#pragma unroll
      for(int ii=0; ii<4; ii++) v[ii] = Vs[ti*4+ii][dc];
      float4 q0 = *(const float4*)&Qs[dc][jt*8];
      float4 q1 = *(const float4*)&Qs[dc][jt*8+4];
      float q[8] = {q0.x,q0.y,q0.z,q0.w,q1.x,q1.y,q1.z,q1.w};
#pragma unroll
      for(int ii=0; ii<4; ii++)
#pragma unroll
        for(int jj=0; jj<8; jj++) acc[ii][jj] += v[ii]*q[jj];
    }
  }
  float* Sb = S + (size_t)b * LC_ * SP;
#pragma unroll
  for(int ii=0; ii<4; ii++){
    int il = ti*4+ii;
    int i  = i0 + il;
    if(i < LC_){
      float t2v = t2s[il];
      float4 o0, o1;
      o0.x=acc[ii][0]+t2v; o0.y=acc[ii][1]+t2v; o0.z=acc[ii][2]+t2v; o0.w=acc[ii][3]+t2v;
      o1.x=acc[ii][4]+t2v; o1.y=acc[ii][5]+t2v; o1.z=acc[ii][6]+t2v; o1.w=acc[ii][7]+t2v;
      if(jt*8   < SP) *(float4*)&Sb[(size_t)i*SP + jt*8    ] = o0;  // j<104 only
      if(jt*8+4 < SP) *(float4*)&Sb[(size_t)i*SP + jt*8 + 4] = o1;
    }
  }
}

// ---------------- K2a: partial column stats (softmax axis=1), 512 blocks ----------------
#define NIC 8
__global__ __launch_bounds__(256) void k_colstats1(const float* __restrict__ S,
                                                   float* __restrict__ pm,
                                                   float* __restrict__ ps){
  __shared__ float lm[8][128], lsum[8][128];
  int b = blockIdx.x, ic = blockIdx.y;
  int tid = threadIdx.x;
  int jt = tid & 31, h = tid >> 5;
  int j0 = jt*4;
  int ni = min(16, 125 - h*16);
  const float* Sb = S + (size_t)b * LC_ * SP;
  float m[4] = {-1e30f,-1e30f,-1e30f,-1e30f}, s[4] = {0.f,0.f,0.f,0.f};
  if(jt < 26){
    for(int r=0;r<ni;r++){
      int i = ic*125 + h*16 + r;
      float4 x = *(const float4*)&Sb[(size_t)i*SP + j0];
      float xv[4] = {x.x,x.y,x.z,x.w};
#pragma unroll
      for(int k=0;k<4;k++){
        if(xv[k] > m[k]){ s[k] = s[k]*__expf(m[k]-xv[k]) + 1.f; m[k] = xv[k]; }
        else              s[k] += __expf(xv[k]-m[k]);
      }
    }
  }
#pragma unroll
  for(int k=0;k<4;k++){
    int j = j0+k;
    if(j < 128){ lm[h][j] = m[k]; lsum[h][j] = s[k]; }
  }
  __syncthreads();
  if(tid < 128){
    float mm = -1e30f, ss = 0.f;
#pragma unroll
    for(int hh=0; hh<8; hh++){
      float m2 = lm[hh][tid], s2 = lsum[hh][tid];
      if(m2 > mm){ ss = ss*__expf(mm-m2) + s2; mm = m2; }
      else         ss += s2*__expf(m2-mm);
    }
    pm[((size_t)b*NIC + ic)*128 + tid] = mm;
    ps[((size_t)b*NIC + ic)*128 + tid] = ss;
  }
}

// ---------------- K2b: combine partials ----------------
__global__ __launch_bounds__(128) void k_colstats2(const float* __restrict__ pm,
                                                   const float* __restrict__ ps,
                                                   float* __restrict__ cm,
                                                   float* __restrict__ cs){
  int b = blockIdx.x, j = threadIdx.x;
  float mm = -1e30f, ss = 0.f;
#pragma unroll
  for(int ic=0; ic<NIC; ic++){
    float m2 = pm[((size_t)b*NIC + ic)*128 + j];
    float s2 = ps[((size_t)b*NIC + ic)*128 + j];
    if(m2 > mm){ ss = ss*__expf(mm-m2) + s2; mm = m2; }
    else         ss += s2*__expf(m2-mm);
  }
  cm[b*JP + j] = mm;
  cs[b*JP + j] = (ss == 0.f) ? 1.f : ss;
}

// ---------------- K3: M[b,j,d] = sum_i softmax_col(S)[i,j]*Ct[i,d] ----------------
#define KCH 125
__global__ __launch_bounds__(256) void k_M(const float* __restrict__ S,
                                           const float* __restrict__ Ct,
                                           const float* __restrict__ cm_,
                                           const float* __restrict__ cs_,
                                           float* __restrict__ M){
  __shared__ float Es[16][132];
  __shared__ float Cs[16][132];
  __shared__ float cml[128], icsl[128];
  int b   = blockIdx.x;
  int ic0 = blockIdx.y * KCH;
  int tid = threadIdx.x;
  if(tid < 128){ cml[tid] = cm_[b*JP+tid]; icsl[tid] = 1.f/cs_[b*JP+tid]; }
  int jt = tid & 15, dtg = tid >> 4;
  float acc[8][8] = {};
  const float* Sb  = S  + (size_t)b * LC_ * SP;
  const float* Ctb = Ct + (size_t)b * LC_ * D_;
  for(int s0=0; s0<KCH; s0+=16){
    int rem = KCH - s0;          // last step: 13
    __syncthreads();
    for(int idx=tid; idx<16*128; idx+=256){
      int ii = idx >> 7, j = idx & 127;
      float e = 0.f;
      if(j < LQ_ && ii < rem){
        int i = ic0 + s0 + ii;
        e = __expf(Sb[(size_t)i*SP + j] - cml[j]);
      }
      Es[ii][j] = e;
    }
    for(int idx=tid; idx<16*128; idx+=256){
      int ii = idx >> 7, dl = idx & 127;
      float v = 0.f;
      if(ii < rem){ int i = ic0 + s0 + ii; v = Ctb[(size_t)i*D_ + dl]; }
      Cs[ii][dl] = v;
    }
    __syncthreads();
#pragma unroll 2
    for(int ii=0; ii<16; ii++){
      float4 e0 = *(const float4*)&Es[ii][jt*8];
      float4 e1 = *(const float4*)&Es[ii][jt*8+4];
      float4 c0 = *(const float4*)&Cs[ii][dtg*8];
      float4 c1 = *(const float4*)&Cs[ii][dtg*8+4];
      float e[8] = {e0.x,e0.y,e0.z,e0.w,e1.x,e1.y,e1.z,e1.w};
      float cc[8] = {c0.x,c0.y,c0.z,c0.w,c1.x,c1.y,c1.z,c1.w};
#pragma unroll
      for(int jj=0; jj<8; jj++)
#pragma unroll
        for(int dd=0; dd<8; dd++) acc[jj][dd] += e[jj]*cc[dd];
    }
  }
  float* Mb = M + (size_t)b * JP * D_;
#pragma unroll
  for(int jj=0; jj<8; jj++){
    int j = jt*8+jj;
    float ics = icsl[j];
#pragma unroll
    for(int dd=0; dd<8; dd++)
      atomicAdd(&Mb[(size_t)j*D_ + dtg*8+dd], acc[jj][dd]*ics);
  }
}

// ---------------- K4: row softmax + A=S1@Qt + Bm=S1@M + assemble output ----------------
// block 256, tile 64 i x 128 d, K chunked over j (16). LDS 43.5KB -> 3 blocks/CU.
__global__ __launch_bounds__(256) void k_final(const float* __restrict__ S,
                                               const float* __restrict__ Qt,
                                               const float* __restrict__ M,
                                               const float* __restrict__ C,
                                               float* __restrict__ out){
  __shared__ float lds[10880];
  float* S1s = lds;            // [64][104]
  float* Qc  = lds + 6656;     // [16][132]
  float* Mc  = lds + 8768;     // [16][132]
  float* At  = lds;            // [64][133] epilogue transpose (reuse)
  int b   = blockIdx.y;
  int i0  = blockIdx.x * 64;
  int tid = threadIdx.x;
  const float* Sb  = S  + (size_t)b * LC_ * SP;
  const float* Qtb = Qt + (size_t)b * LQ_ * D_;
  const float* Mb  = M  + (size_t)b * JP * D_;

  // stage S tile (zero cols 100..103)
  for(int idx=tid; idx<64*26; idx+=256){
    int il = idx / 26, f = idx % 26;
    int i = i0 + il;
    float4 v = make_float4(0.f,0.f,0.f,0.f);
    if(i < LC_ && f < 25) v = *(const float4*)&Sb[(size_t)i*SP + f*4];
    *(float4*)&S1s[il*104 + f*4] = v;
  }
  __syncthreads();

  // in-LDS row softmax over j<100 (4 waves x 16 rows, 2 cols/lane)
  {
    int w = tid >> 6, l = tid & 63;
    for(int r=0; r<16; r++){
      int il = w*16 + r;
      float x0 = (2*l   < LQ_) ? S1s[il*104 + 2*l  ] : -1e30f;
      float x1 = (2*l+1 < LQ_) ? S1s[il*104 + 2*l+1] : -1e30f;
      float m = fmaxf(x0,x1);
#pragma unroll
      for(int mm=32;mm>0;mm>>=1) m = fmaxf(m, __shfl_xor(m, mm, 64));
      float e0 = (2*l   < LQ_) ? __expf(x0-m) : 0.f;
      float e1 = (2*l+1 < LQ_) ? __expf(x1-m) : 0.f;
      float s = e0+e1;
#pragma unroll
      for(int mm=32;mm>0;mm>>=1) s += __shfl_xor(s, mm, 64);
      float inv = 1.f/s;
      if(2*l   < LQ_) S1s[il*104 + 2*l  ] = e0*inv;
      if(2*l+1 < LQ_) S1s[il*104 + 2*l+1] = e1*inv;
    }
  }

  // dual GEMM, K chunked by 16 j
  int dt = tid & 31;   // d = dt*4 + dd
  int it = tid >> 5;   // i_local = it*8 + ii
  float A[8][4] = {}, Bm[8][4] = {};
  for(int j0=0; j0<LQ_; j0+=16){
    int nj = min(16, LQ_-j0);
    __syncthreads();
    for(int idx=tid; idx<nj*32; idx+=256){
      int jj = idx >> 5, f = idx & 31;
      *(float4*)&Qc[jj*132 + f*4] = *(const float4*)&Qtb[(size_t)(j0+jj)*D_ + f*4];
      *(float4*)&Mc[jj*132 + f*4] = *(const float4*)&Mb [(size_t)(j0+jj)*D_ + f*4];
    }
    __syncthreads();
    for(int jj4=0; jj4<nj; jj4+=4){
      float4 sv[8], qv[4], mv[4];
#pragma unroll
      for(int ii=0; ii<8; ii++) sv[ii] = *(const float4*)&S1s[(it*8+ii)*104 + j0+jj4];
#pragma unroll
      for(int jj=0; jj<4; jj++){
        qv[jj] = *(const float4*)&Qc[(jj4+jj)*132 + dt*4];
        mv[jj] = *(const float4*)&Mc[(jj4+jj)*132 + dt*4];
      }
#pragma unroll
      for(int ii=0; ii<8; ii++){
        float sf[4] = {sv[ii].x, sv[ii].y, sv[ii].z, sv[ii].w};
#pragma unroll
        for(int jj=0; jj<4; jj++){
          A[ii][0]  += sf[jj]*qv[jj].x; A[ii][1]  += sf[jj]*qv[jj].y;
          A[ii][2]  += sf[jj]*qv[jj].z; A[ii][3]  += sf[jj]*qv[jj].w;
          Bm[ii][0] += sf[jj]*mv[jj].x; Bm[ii][1] += sf[jj]*mv[jj].y;
          Bm[ii][2] += sf[jj]*mv[jj].z; Bm[ii][3] += sf[jj]*mv[jj].w;
        }
      }
    }
  }

  // epilogue: two LDS round-trips (A then Bm), odd stride 133 -> conflict-free reads
  const float* Cb = C + (size_t)b * D_ * LC_;
  float* ob = out + (size_t)b * 512 * LC_;
  int il2 = tid & 63, dg = tid >> 6;
  int i = i0 + il2;

  __syncthreads();
#pragma unroll
  for(int ii=0; ii<8; ii++)
#pragma unroll
    for(int dd=0; dd<4; dd++) At[(it*8+ii)*133 + dt*4+dd] = A[ii][dd];
  __syncthreads();
  if(i < LC_){
    for(int dd2=0; dd2<32; dd2++){
      int d = dg*32 + dd2;
      float a = At[il2*133 + d];
      float c = Cb[(size_t)d*LC_ + i];
      ob[(size_t)d*LC_ + i]       = c;
      ob[(size_t)(128+d)*LC_ + i] = a;
      ob[(size_t)(256+d)*LC_ + i] = c*a;
    }
  }
  __syncthreads();
#pragma unroll
  for(int ii=0; ii<8; ii++)
#pragma unroll
    for(int dd=0; dd<4; dd++) At[(it*8+ii)*133 + dt*4+dd] = Bm[ii][dd];
  __syncthreads();
  if(i < LC_){
    for(int dd2=0; dd2<32; dd2++){
      int d = dg*32 + dd2;
      float bm = At[il2*133 + d];
      float c  = Cb[(size_t)d*LC_ + i];
      ob[(size_t)(384+d)*LC_ + i] = c*bm;
    }
  }
}

extern "C" void kernel_launch(void* const* d_in, const int* in_sizes, int n_in,
                              void* d_out, int out_size, void* d_ws, size_t ws_size,
                              hipStream_t stream){
  const float* C = (const float*)d_in[0];
  const float* Q = (const float*)d_in[1];
  const float* W = (const float*)d_in[2];
  float* out = (float*)d_out;
  float* ws  = (float*)d_ws;
  // ws layout (floats): S 6.656M | Ct 8.192M | M 1.049M | Qt 0.819M | pm/ps 65.5K*2 | cm/cs 8.2K*2 = 67.5 MB
  float* S  = ws;
  float* Ct = ws + 6656000;
  float* M  = ws + 14848000;
  float* Qt = ws + 15896576;
  float* pm = ws + 16715776;
  float* ps = ws + 16781312;
  float* cm = ws + 16846848;
  float* cs = ws + 16855040;

  hipMemsetAsync(M, 0, (size_t)JP*D_*B_*sizeof(float), stream);
  k_transpose <<<dim3(32,4,64), dim3(32,8), 0, stream>>>(C, Ct);
  k_transposeQ<<<dim3(4,4,64),  dim3(32,8), 0, stream>>>(Q, Qt);
  k_S         <<<dim3(16,64),   256, 0, stream>>>(Q, W, Ct, S);
  k_colstats1 <<<dim3(64,NIC),  256, 0, stream>>>(S, pm, ps);
  k_colstats2 <<<64,            128, 0, stream>>>(pm, ps, cm, cs);
  k_M         <<<dim3(64,NIC),  256, 0, stream>>>(S, Ct, cm, cs, M);
  k_final     <<<dim3(16,64),   256, 0, stream>>>(S, Qt, M, C, out);
}

// Round 5
// 497.251 us; speedup vs baseline: 1.6862x; 1.2491x over previous
//
#include <hip/hip_runtime.h>
#include <cstddef>

#define B_  64
#define D_  128
#define LC_ 1000
#define LQ_ 100
#define SP  104   // S row stride (padded LQ, mult of 8)
#define JP  128   // cm/cs stride

// ---------------- K0: transpose C (B,D,LC) -> Ct (B,LC,D) ----------------
__global__ __launch_bounds__(256) void k_transpose(const float* __restrict__ C,
                                                   float* __restrict__ Ct){
  __shared__ float t[32][33];
  int b  = blockIdx.z;
  int i0 = blockIdx.x * 32;
  int d0 = blockIdx.y * 32;
  int tx = threadIdx.x, ty = threadIdx.y;
  const float* Cb  = C  + (size_t)b * D_ * LC_;
  float*       Ctb = Ct + (size_t)b * LC_ * D_;
#pragma unroll
  for(int k=0;k<4;k++){
    int d = d0 + ty + 8*k;
    int i = i0 + tx;
    t[ty+8*k][tx] = (i < LC_) ? Cb[(size_t)d*LC_ + i] : 0.f;
  }
  __syncthreads();
#pragma unroll
  for(int k=0;k<4;k++){
    int i = i0 + ty + 8*k;
    int d = d0 + tx;
    if(i < LC_) Ctb[(size_t)i*D_ + d] = t[tx][ty+8*k];
  }
}

// ---------------- K0b: transpose Q (B,D,LQ) -> Qt (B,LQ,D) ----------------
__global__ __launch_bounds__(256) void k_transposeQ(const float* __restrict__ Q,
                                                    float* __restrict__ Qt){
  __shared__ float t[32][33];
  int b  = blockIdx.z;
  int j0 = blockIdx.x * 32;
  int d0 = blockIdx.y * 32;
  int tx = threadIdx.x, ty = threadIdx.y;
  const float* Qb  = Q  + (size_t)b * D_ * LQ_;
  float*       Qtb = Qt + (size_t)b * LQ_ * D_;
#pragma unroll
  for(int k=0;k<4;k++){
    int d = d0 + ty + 8*k;
    int j = j0 + tx;
    t[ty+8*k][tx] = (j < LQ_) ? Qb[(size_t)d*LQ_ + j] : 0.f;
  }
  __syncthreads();
#pragma unroll
  for(int k=0;k<4;k++){
    int j = j0 + ty + 8*k;
    int d = d0 + tx;
    if(j < LQ_) Qtb[(size_t)j*D_ + d] = t[tx][ty+8*k];
  }
}

// ---------------- K1: S[b,i,j] = sum_d (w1+w3*Ct)[i,d]*Q[d,j] + t2[i] ----------------
__global__ __launch_bounds__(256) void k_S(const float* __restrict__ Q,
                                           const float* __restrict__ W,
                                           const float* __restrict__ Ct,
                                           float* __restrict__ S){
  __shared__ float Qs[32][132];
  __shared__ float Vs[64][33];
  __shared__ float t2s[64];
  int b   = blockIdx.y;
  int i0  = blockIdx.x * 64;
  int tid = threadIdx.x;
  const float* Wb  = W  + (size_t)b * LC_ * 384;
  const float* Ctb = Ct + (size_t)b * LC_ * D_;
  const float* Qb  = Q  + (size_t)b * D_ * LQ_;

  // t2[i] = sum_d w2[i,d]*Ct[i,d]
  {
    int g = tid >> 5, l = tid & 31;
    for(int rep=0; rep<8; rep++){
      int il = rep*8 + g;
      int i  = i0 + il;
      float s = 0.f;
      if(i < LC_){
        const float* wrow  = Wb  + (size_t)i*384 + 128;
        const float* ctrow = Ctb + (size_t)i*D_;
#pragma unroll
        for(int k=0;k<4;k++){ int d = l + 32*k; s += wrow[d]*ctrow[d]; }
      }
#pragma unroll
      for(int m=16;m>0;m>>=1) s += __shfl_xor(s, m, 64);
      if(l==0) t2s[il] = s;
    }
  }

  int jt = tid & 15;
  int ti = tid >> 4;
  float acc[4][8] = {};

  for(int c=0;c<4;c++){
    int dc0 = c*32;
    __syncthreads();
    for(int idx=tid; idx<32*128; idx+=256){
      int dc = idx >> 7, j = idx & 127;
      Qs[dc][j] = (j < LQ_) ? Qb[(size_t)(dc0+dc)*LQ_ + j] : 0.f;
    }
    for(int idx=tid; idx<64*32; idx+=256){
      int il = idx >> 5, dc = idx & 31;
      int i = i0 + il;
      float v = 0.f;
      if(i < LC_){
        const float* wrow = Wb + (size_t)i*384;
        float ct = Ctb[(size_t)i*D_ + dc0+dc];
        v = wrow[dc0+dc] + wrow[256+dc0+dc]*ct;
      }
      Vs[il][dc] = v;
    }
    __syncthreads();
#pragma unroll 4
    for(int dc=0; dc<32; dc++){
      float v[4];
#pragma unroll
      for(int ii=0; ii<4; ii++) v[ii] = Vs[ti*4+ii][dc];
      float4 q0 = *(const float4*)&Qs[dc][jt*8];
      float4 q1 = *(const float4*)&Qs[dc][jt*8+4];
      float q[8] = {q0.x,q0.y,q0.z,q0.w,q1.x,q1.y,q1.z,q1.w};
#pragma unroll
      for(int ii=0; ii<4; ii++)
#pragma unroll
        for(int jj=0; jj<8; jj++) acc[ii][jj] += v[ii]*q[jj];
    }
  }
  float* Sb = S + (size_t)b * LC_ * SP;
#pragma unroll
  for(int ii=0; ii<4; ii++){
    int il = ti*4+ii;
    int i  = i0 + il;
    if(i < LC_){
      float t2v = t2s[il];
      float4 o0, o1;
      o0.x=acc[ii][0]+t2v; o0.y=acc[ii][1]+t2v; o0.z=acc[ii][2]+t2v; o0.w=acc[ii][3]+t2v;
      o1.x=acc[ii][4]+t2v; o1.y=acc[ii][5]+t2v; o1.z=acc[ii][6]+t2v; o1.w=acc[ii][7]+t2v;
      if(jt*8   < SP) *(float4*)&Sb[(size_t)i*SP + jt*8    ] = o0;  // j<104 only
      if(jt*8+4 < SP) *(float4*)&Sb[(size_t)i*SP + jt*8 + 4] = o1;
    }
  }
}

// ---------------- K2a: partial column stats (softmax axis=1) ----------------
#define NIC 8
__global__ __launch_bounds__(256) void k_colstats1(const float* __restrict__ S,
                                                   float* __restrict__ pm,
                                                   float* __restrict__ ps){
  __shared__ float lm[8][128], lsum[8][128];
  int b = blockIdx.x, ic = blockIdx.y;
  int tid = threadIdx.x;
  int jt = tid & 31, h = tid >> 5;
  int j0 = jt*4;
  int ni = min(16, 125 - h*16);
  const float* Sb = S + (size_t)b * LC_ * SP;
  float m[4] = {-1e30f,-1e30f,-1e30f,-1e30f}, s[4] = {0.f,0.f,0.f,0.f};
  if(jt < 26){
    for(int r=0;r<ni;r++){
      int i = ic*125 + h*16 + r;
      float4 x = *(const float4*)&Sb[(size_t)i*SP + j0];
      float xv[4] = {x.x,x.y,x.z,x.w};
#pragma unroll
      for(int k=0;k<4;k++){
        if(xv[k] > m[k]){ s[k] = s[k]*__expf(m[k]-xv[k]) + 1.f; m[k] = xv[k]; }
        else              s[k] += __expf(xv[k]-m[k]);
      }
    }
  }
#pragma unroll
  for(int k=0;k<4;k++){
    int j = j0+k;
    if(j < 128){ lm[h][j] = m[k]; lsum[h][j] = s[k]; }
  }
  __syncthreads();
  if(tid < 128){
    float mm = -1e30f, ss = 0.f;
#pragma unroll
    for(int hh=0; hh<8; hh++){
      float m2 = lm[hh][tid], s2 = lsum[hh][tid];
      if(m2 > mm){ ss = ss*__expf(mm-m2) + s2; mm = m2; }
      else         ss += s2*__expf(m2-mm);
    }
    pm[((size_t)b*NIC + ic)*128 + tid] = mm;
    ps[((size_t)b*NIC + ic)*128 + tid] = ss;
  }
}

// ---------------- K2b: combine partials ----------------
__global__ __launch_bounds__(128) void k_colstats2(const float* __restrict__ pm,
                                                   const float* __restrict__ ps,
                                                   float* __restrict__ cm,
                                                   float* __restrict__ cs){
  int b = blockIdx.x, j = threadIdx.x;
  float mm = -1e30f, ss = 0.f;
#pragma unroll
  for(int ic=0; ic<NIC; ic++){
    float m2 = pm[((size_t)b*NIC + ic)*128 + j];
    float s2 = ps[((size_t)b*NIC + ic)*128 + j];
    if(m2 > mm){ ss = ss*__expf(mm-m2) + s2; mm = m2; }
    else         ss += s2*__expf(m2-mm);
  }
  cm[b*JP + j] = mm;
  cs[b*JP + j] = (ss == 0.f) ? 1.f : ss;
}

// ---------------- K3: M[b,j,d] = sum_i softmax_col(S)[i,j]*Ct[i,d] ----------------
// j-split: grid (b, jq) with 25 j-columns per block, full i=1000 reduction,
// plain coalesced stores (NO atomics -- device-scope atomic RMW was 256MB of
// HBM write traffic and 270us in round 3).
#define MJQ 25
__global__ __launch_bounds__(256) void k_Mj(const float* __restrict__ S,
                                            const float* __restrict__ Ct,
                                            const float* __restrict__ cm_,
                                            const float* __restrict__ cs_,
                                            float* __restrict__ M){
  __shared__ float Es[32][32];    // [i-chunk][j_local]
  __shared__ float Cs[32][132];   // [i-chunk][d]
  __shared__ float cml[32], icsl[32];
  int b  = blockIdx.x;
  int jq = blockIdx.y;
  int j0 = jq * MJQ;
  int tid = threadIdx.x;
  if(tid < 32){
    int j = j0 + tid;
    cml[tid]  = (tid < MJQ && j < LQ_) ? cm_[b*JP + j] : 0.f;
    icsl[tid] = (tid < MJQ && j < LQ_) ? 1.f/cs_[b*JP + j] : 0.f;
  }
  __syncthreads();
  int dt = tid & 31;   // d = dt*4 + dd
  int jt = tid >> 5;   // j_local = jt*4 + jj
  float acc[4][4] = {};
  const float* Sb  = S  + (size_t)b * LC_ * SP + j0;
  const float* Ctb = Ct + (size_t)b * LC_ * D_;

  for(int i0=0; i0<LC_; i0+=32){
    int rem = min(32, LC_ - i0);
    __syncthreads();
    for(int idx=tid; idx<32*32; idx+=256){
      int ii = idx >> 5, jl = idx & 31;
      float e = 0.f;
      if(ii < rem && jl < MJQ && (j0+jl) < LQ_)
        e = __expf(Sb[(size_t)(i0+ii)*SP + jl] - cml[jl]);
      Es[ii][jl] = e;
    }
    for(int idx=tid; idx<32*32; idx+=256){
      int ii = idx >> 5, f = idx & 31;
      float4 v = make_float4(0.f,0.f,0.f,0.f);
      if(ii < rem) v = *(const float4*)&Ctb[(size_t)(i0+ii)*D_ + f*4];
      *(float4*)&Cs[ii][f*4] = v;
    }
    __syncthreads();
#pragma unroll 8
    for(int ii=0; ii<32; ii++){
      float4 e4 = *(const float4*)&Es[ii][jt*4];
      float4 c4 = *(const float4*)&Cs[ii][dt*4];
      float e[4] = {e4.x,e4.y,e4.z,e4.w};
      float c[4] = {c4.x,c4.y,c4.z,c4.w};
#pragma unroll
      for(int jj=0; jj<4; jj++)
#pragma unroll
        for(int dd=0; dd<4; dd++) acc[jj][dd] += e[jj]*c[dd];
    }
  }
  float* Mb = M + (size_t)b * JP * D_;
#pragma unroll
  for(int jj=0; jj<4; jj++){
    int jl = jt*4 + jj;
    if(jl < MJQ && (j0+jl) < LQ_){
      float ics = icsl[jl];
      float4 o;
      o.x = acc[jj][0]*ics; o.y = acc[jj][1]*ics;
      o.z = acc[jj][2]*ics; o.w = acc[jj][3]*ics;
      *(float4*)&Mb[(size_t)(j0+jl)*D_ + dt*4] = o;
    }
  }
}

// ---------------- K4: row softmax + A=S1@Qt + Bm=S1@M + assemble output ----------------
__global__ __launch_bounds__(256) void k_final(const float* __restrict__ S,
                                               const float* __restrict__ Qt,
                                               const float* __restrict__ M,
                                               const float* __restrict__ C,
                                               float* __restrict__ out){
  __shared__ float lds[10880];
  float* S1s = lds;            // [64][104]
  float* Qc  = lds + 6656;     // [16][132]
  float* Mc  = lds + 8768;     // [16][132]
  float* At  = lds;            // [64][133] epilogue transpose (reuse)
  int b   = blockIdx.y;
  int i0  = blockIdx.x * 64;
  int tid = threadIdx.x;
  const float* Sb  = S  + (size_t)b * LC_ * SP;
  const float* Qtb = Qt + (size_t)b * LQ_ * D_;
  const float* Mb  = M  + (size_t)b * JP * D_;

  for(int idx=tid; idx<64*26; idx+=256){
    int il = idx / 26, f = idx % 26;
    int i = i0 + il;
    float4 v = make_float4(0.f,0.f,0.f,0.f);
    if(i < LC_ && f < 25) v = *(const float4*)&Sb[(size_t)i*SP + f*4];
    *(float4*)&S1s[il*104 + f*4] = v;
  }
  __syncthreads();

  {
    int w = tid >> 6, l = tid & 63;
    for(int r=0; r<16; r++){
      int il = w*16 + r;
      float x0 = (2*l   < LQ_) ? S1s[il*104 + 2*l  ] : -1e30f;
      float x1 = (2*l+1 < LQ_) ? S1s[il*104 + 2*l+1] : -1e30f;
      float m = fmaxf(x0,x1);
#pragma unroll
      for(int mm=32;mm>0;mm>>=1) m = fmaxf(m, __shfl_xor(m, mm, 64));
      float e0 = (2*l   < LQ_) ? __expf(x0-m) : 0.f;
      float e1 = (2*l+1 < LQ_) ? __expf(x1-m) : 0.f;
      float s = e0+e1;
#pragma unroll
      for(int mm=32;mm>0;mm>>=1) s += __shfl_xor(s, mm, 64);
      float inv = 1.f/s;
      if(2*l   < LQ_) S1s[il*104 + 2*l  ] = e0*inv;
      if(2*l+1 < LQ_) S1s[il*104 + 2*l+1] = e1*inv;
    }
  }

  int dt = tid & 31;
  int it = tid >> 5;
  float A[8][4] = {}, Bm[8][4] = {};
  for(int j0=0; j0<LQ_; j0+=16){
    int nj = min(16, LQ_-j0);
    __syncthreads();
    for(int idx=tid; idx<nj*32; idx+=256){
      int jj = idx >> 5, f = idx & 31;
      *(float4*)&Qc[jj*132 + f*4] = *(const float4*)&Qtb[(size_t)(j0+jj)*D_ + f*4];
      *(float4*)&Mc[jj*132 + f*4] = *(const float4*)&Mb [(size_t)(j0+jj)*D_ + f*4];
    }
    __syncthreads();
    for(int jj4=0; jj4<nj; jj4+=4){
      float4 sv[8], qv[4], mv[4];
#pragma unroll
      for(int ii=0; ii<8; ii++) sv[ii] = *(const float4*)&S1s[(it*8+ii)*104 + j0+jj4];
#pragma unroll
      for(int jj=0; jj<4; jj++){
        qv[jj] = *(const float4*)&Qc[(jj4+jj)*132 + dt*4];
        mv[jj] = *(const float4*)&Mc[(jj4+jj)*132 + dt*4];
      }
#pragma unroll
      for(int ii=0; ii<8; ii++){
        float sf[4] = {sv[ii].x, sv[ii].y, sv[ii].z, sv[ii].w};
#pragma unroll
        for(int jj=0; jj<4; jj++){
          A[ii][0]  += sf[jj]*qv[jj].x; A[ii][1]  += sf[jj]*qv[jj].y;
          A[ii][2]  += sf[jj]*qv[jj].z; A[ii][3]  += sf[jj]*qv[jj].w;
          Bm[ii][0] += sf[jj]*mv[jj].x; Bm[ii][1] += sf[jj]*mv[jj].y;
          Bm[ii][2] += sf[jj]*mv[jj].z; Bm[ii][3] += sf[jj]*mv[jj].w;
        }
      }
    }
  }

  const float* Cb = C + (size_t)b * D_ * LC_;
  float* ob = out + (size_t)b * 512 * LC_;
  int il2 = tid & 63, dg = tid >> 6;
  int i = i0 + il2;

  __syncthreads();
#pragma unroll
  for(int ii=0; ii<8; ii++)
#pragma unroll
    for(int dd=0; dd<4; dd++) At[(it*8+ii)*133 + dt*4+dd] = A[ii][dd];
  __syncthreads();
  if(i < LC_){
    for(int dd2=0; dd2<32; dd2++){
      int d = dg*32 + dd2;
      float a = At[il2*133 + d];
      float c = Cb[(size_t)d*LC_ + i];
      ob[(size_t)d*LC_ + i]       = c;
      ob[(size_t)(128+d)*LC_ + i] = a;
      ob[(size_t)(256+d)*LC_ + i] = c*a;
    }
  }
  __syncthreads();
#pragma unroll
  for(int ii=0; ii<8; ii++)
#pragma unroll
    for(int dd=0; dd<4; dd++) At[(it*8+ii)*133 + dt*4+dd] = Bm[ii][dd];
  __syncthreads();
  if(i < LC_){
    for(int dd2=0; dd2<32; dd2++){
      int d = dg*32 + dd2;
      float bm = At[il2*133 + d];
      float c  = Cb[(size_t)d*LC_ + i];
      ob[(size_t)(384+d)*LC_ + i] = c*bm;
    }
  }
}

extern "C" void kernel_launch(void* const* d_in, const int* in_sizes, int n_in,
                              void* d_out, int out_size, void* d_ws, size_t ws_size,
                              hipStream_t stream){
  const float* C = (const float*)d_in[0];
  const float* Q = (const float*)d_in[1];
  const float* W = (const float*)d_in[2];
  float* out = (float*)d_out;
  float* ws  = (float*)d_ws;
  // ws layout (floats): S 6.656M | Ct 8.192M | M 1.049M | Qt 0.819M | pm/ps 65.5K*2 | cm/cs 8.2K*2 = 67.5 MB
  float* S  = ws;
  float* Ct = ws + 6656000;
  float* M  = ws + 14848000;
  float* Qt = ws + 15896576;
  float* pm = ws + 16715776;
  float* ps = ws + 16781312;
  float* cm = ws + 16846848;
  float* cs = ws + 16855040;

  k_transpose <<<dim3(32,4,64), dim3(32,8), 0, stream>>>(C, Ct);
  k_transposeQ<<<dim3(4,4,64),  dim3(32,8), 0, stream>>>(Q, Qt);
  k_S         <<<dim3(16,64),   256, 0, stream>>>(Q, W, Ct, S);
  k_colstats1 <<<dim3(64,NIC),  256, 0, stream>>>(S, pm, ps);
  k_colstats2 <<<64,            128, 0, stream>>>(pm, ps, cm, cs);
  k_Mj        <<<dim3(64,4),    256, 0, stream>>>(S, Ct, cm, cs, M);
  k_final     <<<dim3(16,64),   256, 0, stream>>>(S, Qt, M, C, out);
}

// Round 6
// 421.090 us; speedup vs baseline: 1.9912x; 1.1809x over previous
//
#include <hip/hip_runtime.h>
#include <cstddef>

#define B_  64
#define D_  128
#define LC_ 1000
#define LQ_ 100
#define SP  104   // S row stride (padded LQ, mult of 8)
#define JP  128   // cm/cs stride

// ---------------- K0: transpose C (B,D,LC) -> Ct (B,LC,D) ----------------
__global__ __launch_bounds__(256) void k_transpose(const float* __restrict__ C,
                                                   float* __restrict__ Ct){
  __shared__ float t[32][33];
  int b  = blockIdx.z;
  int i0 = blockIdx.x * 32;
  int d0 = blockIdx.y * 32;
  int tx = threadIdx.x, ty = threadIdx.y;
  const float* Cb  = C  + (size_t)b * D_ * LC_;
  float*       Ctb = Ct + (size_t)b * LC_ * D_;
#pragma unroll
  for(int k=0;k<4;k++){
    int d = d0 + ty + 8*k;
    int i = i0 + tx;
    t[ty+8*k][tx] = (i < LC_) ? Cb[(size_t)d*LC_ + i] : 0.f;
  }
  __syncthreads();
#pragma unroll
  for(int k=0;k<4;k++){
    int i = i0 + ty + 8*k;
    int d = d0 + tx;
    if(i < LC_) Ctb[(size_t)i*D_ + d] = t[tx][ty+8*k];
  }
}

// ---------------- K0b: transpose Q (B,D,LQ) -> Qt (B,LQ,D) ----------------
__global__ __launch_bounds__(256) void k_transposeQ(const float* __restrict__ Q,
                                                    float* __restrict__ Qt){
  __shared__ float t[32][33];
  int b  = blockIdx.z;
  int j0 = blockIdx.x * 32;
  int d0 = blockIdx.y * 32;
  int tx = threadIdx.x, ty = threadIdx.y;
  const float* Qb  = Q  + (size_t)b * D_ * LQ_;
  float*       Qtb = Qt + (size_t)b * LQ_ * D_;
#pragma unroll
  for(int k=0;k<4;k++){
    int d = d0 + ty + 8*k;
    int j = j0 + tx;
    t[ty+8*k][tx] = (j < LQ_) ? Qb[(size_t)d*LQ_ + j] : 0.f;
  }
  __syncthreads();
#pragma unroll
  for(int k=0;k<4;k++){
    int j = j0 + ty + 8*k;
    int d = d0 + tx;
    if(j < LQ_) Qtb[(size_t)j*D_ + d] = t[tx][ty+8*k];
  }
}

// ---------------- K1: S[b,i,j] = sum_d (w1+w3*Ct)[i,d]*Q[d,j] + t2[i] ----------------
__global__ __launch_bounds__(256) void k_S(const float* __restrict__ Q,
                                           const float* __restrict__ W,
                                           const float* __restrict__ Ct,
                                           float* __restrict__ S){
  __shared__ float Qs[32][132];
  __shared__ float Vs[64][33];
  __shared__ float t2s[64];
  int b   = blockIdx.y;
  int i0  = blockIdx.x * 64;
  int tid = threadIdx.x;
  const float* Wb  = W  + (size_t)b * LC_ * 384;
  const float* Ctb = Ct + (size_t)b * LC_ * D_;
  const float* Qb  = Q  + (size_t)b * D_ * LQ_;

  // t2[i] = sum_d w2[i,d]*Ct[i,d]
  {
    int g = tid >> 5, l = tid & 31;
    for(int rep=0; rep<8; rep++){
      int il = rep*8 + g;
      int i  = i0 + il;
      float s = 0.f;
      if(i < LC_){
        const float* wrow  = Wb  + (size_t)i*384 + 128;
        const float* ctrow = Ctb + (size_t)i*D_;
#pragma unroll
        for(int k=0;k<4;k++){ int d = l + 32*k; s += wrow[d]*ctrow[d]; }
      }
#pragma unroll
      for(int m=16;m>0;m>>=1) s += __shfl_xor(s, m, 64);
      if(l==0) t2s[il] = s;
    }
  }

  int jt = tid & 15;
  int ti = tid >> 4;
  float acc[4][8] = {};

  for(int c=0;c<4;c++){
    int dc0 = c*32;
    __syncthreads();
    for(int idx=tid; idx<32*128; idx+=256){
      int dc = idx >> 7, j = idx & 127;
      Qs[dc][j] = (j < LQ_) ? Qb[(size_t)(dc0+dc)*LQ_ + j] : 0.f;
    }
    for(int idx=tid; idx<64*32; idx+=256){
      int il = idx >> 5, dc = idx & 31;
      int i = i0 + il;
      float v = 0.f;
      if(i < LC_){
        const float* wrow = Wb + (size_t)i*384;
        float ct = Ctb[(size_t)i*D_ + dc0+dc];
        v = wrow[dc0+dc] + wrow[256+dc0+dc]*ct;
      }
      Vs[il][dc] = v;
    }
    __syncthreads();
#pragma unroll 4
    for(int dc=0; dc<32; dc++){
      float v[4];
#pragma unroll
      for(int ii=0; ii<4; ii++) v[ii] = Vs[ti*4+ii][dc];
      float4 q0 = *(const float4*)&Qs[dc][jt*8];
      float4 q1 = *(const float4*)&Qs[dc][jt*8+4];
      float q[8] = {q0.x,q0.y,q0.z,q0.w,q1.x,q1.y,q1.z,q1.w};
#pragma unroll
      for(int ii=0; ii<4; ii++)
#pragma unroll
        for(int jj=0; jj<8; jj++) acc[ii][jj] += v[ii]*q[jj];
    }
  }
  float* Sb = S + (size_t)b * LC_ * SP;
#pragma unroll
  for(int ii=0; ii<4; ii++){
    int il = ti*4+ii;
    int i  = i0 + il;
    if(i < LC_){
      float t2v = t2s[il];
      float4 o0, o1;
      o0.x=acc[ii][0]+t2v; o0.y=acc[ii][1]+t2v; o0.z=acc[ii][2]+t2v; o0.w=acc[ii][3]+t2v;
      o1.x=acc[ii][4]+t2v; o1.y=acc[ii][5]+t2v; o1.z=acc[ii][6]+t2v; o1.w=acc[ii][7]+t2v;
      if(jt*8   < SP) *(float4*)&Sb[(size_t)i*SP + jt*8    ] = o0;  // j<104 only
      if(jt*8+4 < SP) *(float4*)&Sb[(size_t)i*SP + jt*8 + 4] = o1;
    }
  }
}

// ---------------- K2a: partial column stats (softmax axis=1) ----------------
#define NIC 8
__global__ __launch_bounds__(256) void k_colstats1(const float* __restrict__ S,
                                                   float* __restrict__ pm,
                                                   float* __restrict__ ps){
  __shared__ float lm[8][128], lsum[8][128];
  int b = blockIdx.x, ic = blockIdx.y;
  int tid = threadIdx.x;
  int jt = tid & 31, h = tid >> 5;
  int j0 = jt*4;
  int ni = min(16, 125 - h*16);
  const float* Sb = S + (size_t)b * LC_ * SP;
  float m[4] = {-1e30f,-1e30f,-1e30f,-1e30f}, s[4] = {0.f,0.f,0.f,0.f};
  if(jt < 26){
    for(int r=0;r<ni;r++){
      int i = ic*125 + h*16 + r;
      float4 x = *(const float4*)&Sb[(size_t)i*SP + j0];
      float xv[4] = {x.x,x.y,x.z,x.w};
#pragma unroll
      for(int k=0;k<4;k++){
        if(xv[k] > m[k]){ s[k] = s[k]*__expf(m[k]-xv[k]) + 1.f; m[k] = xv[k]; }
        else              s[k] += __expf(xv[k]-m[k]);
      }
    }
  }
#pragma unroll
  for(int k=0;k<4;k++){
    int j = j0+k;
    if(j < 128){ lm[h][j] = m[k]; lsum[h][j] = s[k]; }
  }
  __syncthreads();
  if(tid < 128){
    float mm = -1e30f, ss = 0.f;
#pragma unroll
    for(int hh=0; hh<8; hh++){
      float m2 = lm[hh][tid], s2 = lsum[hh][tid];
      if(m2 > mm){ ss = ss*__expf(mm-m2) + s2; mm = m2; }
      else         ss += s2*__expf(m2-mm);
    }
    pm[((size_t)b*NIC + ic)*128 + tid] = mm;
    ps[((size_t)b*NIC + ic)*128 + tid] = ss;
  }
}

// ---------------- K2b: combine partials ----------------
__global__ __launch_bounds__(128) void k_colstats2(const float* __restrict__ pm,
                                                   const float* __restrict__ ps,
                                                   float* __restrict__ cm,
                                                   float* __restrict__ cs){
  int b = blockIdx.x, j = threadIdx.x;
  float mm = -1e30f, ss = 0.f;
#pragma unroll
  for(int ic=0; ic<NIC; ic++){
    float m2 = pm[((size_t)b*NIC + ic)*128 + j];
    float s2 = ps[((size_t)b*NIC + ic)*128 + j];
    if(m2 > mm){ ss = ss*__expf(mm-m2) + s2; mm = m2; }
    else         ss += s2*__expf(m2-mm);
  }
  cm[b*JP + j] = mm;
  cs[b*JP + j] = (ss == 0.f) ? 1.f : ss;
}

// ---------------- K3: M[b,j,d] = sum_i softmax_col(S)[i,j]*Ct[i,d] ----------------
// 1024-thread blocks, grid (b, 4 jq). i=1000 split across 4 groups of 4 waves
// (250 rows each, own Es/Cs LDS); register-accumulate, then 4-stage LDS reduce.
// Was: 256-thr blocks, 1 blk/CU, 11% occupancy, 136us (latency-bound).
#define MJQ 25
__global__ __launch_bounds__(1024) void k_Mj(const float* __restrict__ S,
                                             const float* __restrict__ Ct,
                                             const float* __restrict__ cm_,
                                             const float* __restrict__ cs_,
                                             float* __restrict__ M){
  __shared__ float Es[4][16][32];    // [grp][i-chunk][j_local]
  __shared__ float Cs[4][16][132];   // [grp][i-chunk][d]
  __shared__ float Macc[25][132];    // cross-group accumulation tile
  __shared__ float cml[32], icsl[32];
  int b  = blockIdx.x;
  int jq = blockIdx.y;
  int j0 = jq * MJQ;
  int tid = threadIdx.x;             // 0..1023
  int grp = tid >> 8;                // 0..3 (i-range group)
  int t   = tid & 255;
  if(tid < 32){
    int j = j0 + tid;
    cml[tid]  = (tid < MJQ && j < LQ_) ? cm_[b*JP + j] : 0.f;
    icsl[tid] = (tid < MJQ && j < LQ_) ? 1.f/cs_[b*JP + j] : 0.f;
  }
  __syncthreads();
  int dt = t & 31;   // d = dt*4 + dd
  int jt = t >> 5;   // j_local = jt*4 + jj (0..31, mask < MJQ)
  float acc[4][4] = {};
  const float* Sb  = S  + (size_t)b * LC_ * SP + j0;
  const float* Ctb = Ct + (size_t)b * LC_ * D_;
  int ibase = grp * 250;

  for(int i0=0; i0<250; i0+=16){
    int rem = min(16, 250 - i0);
    __syncthreads();
    // stage exp(S - cm) for this group's 16 rows x 25 cols
    for(int idx=t; idx<16*32; idx+=256){
      int ii = idx >> 5, jl = idx & 31;
      float e = 0.f;
      if(ii < rem && jl < MJQ)
        e = __expf(Sb[(size_t)(ibase+i0+ii)*SP + jl] - cml[jl]);
      Es[grp][ii][jl] = e;
    }
    // stage Ct rows (float4 coalesced)
    for(int idx=t; idx<16*32; idx+=256){
      int ii = idx >> 5, f = idx & 31;
      float4 v = make_float4(0.f,0.f,0.f,0.f);
      if(ii < rem) v = *(const float4*)&Ctb[(size_t)(ibase+i0+ii)*D_ + f*4];
      *(float4*)&Cs[grp][ii][f*4] = v;
    }
    __syncthreads();
#pragma unroll
    for(int ii=0; ii<16; ii++){
      float4 e4 = *(const float4*)&Es[grp][ii][jt*4];
      float4 c4 = *(const float4*)&Cs[grp][ii][dt*4];
      float e[4] = {e4.x,e4.y,e4.z,e4.w};
      float c[4] = {c4.x,c4.y,c4.z,c4.w};
#pragma unroll
      for(int jj=0; jj<4; jj++)
#pragma unroll
        for(int dd=0; dd<4; dd++) acc[jj][dd] += e[jj]*c[dd];
    }
  }

  // cross-group reduce (turn-taking; deterministic)
  for(int g=0; g<4; g++){
    if(grp == g){
#pragma unroll
      for(int jj=0; jj<4; jj++){
        int jl = jt*4 + jj;
        if(jl < MJQ){
#pragma unroll
          for(int dd=0; dd<4; dd++){
            if(g == 0) Macc[jl][dt*4+dd]  = acc[jj][dd];
            else       Macc[jl][dt*4+dd] += acc[jj][dd];
          }
        }
      }
    }
    __syncthreads();
  }
  if(grp == 0){
    float* Mb = M + (size_t)b * JP * D_;
#pragma unroll
    for(int jj=0; jj<4; jj++){
      int jl = jt*4 + jj;
      if(jl < MJQ && (j0+jl) < LQ_){
        float ics = icsl[jl];
        float4 o;
        o.x = Macc[jl][dt*4+0]*ics; o.y = Macc[jl][dt*4+1]*ics;
        o.z = Macc[jl][dt*4+2]*ics; o.w = Macc[jl][dt*4+3]*ics;
        *(float4*)&Mb[(size_t)(j0+jl)*D_ + dt*4] = o;
      }
    }
  }
}

// ---------------- K4: row softmax + A=S1@Qt + Bm=S1@M + assemble output ----------------
__global__ __launch_bounds__(256) void k_final(const float* __restrict__ S,
                                               const float* __restrict__ Qt,
                                               const float* __restrict__ M,
                                               const float* __restrict__ C,
                                               float* __restrict__ out){
  __shared__ float lds[10880];
  float* S1s = lds;            // [64][104]
  float* Qc  = lds + 6656;     // [16][132]
  float* Mc  = lds + 8768;     // [16][132]
  float* At  = lds;            // [64][133] epilogue transpose (reuse)
  int b   = blockIdx.y;
  int i0  = blockIdx.x * 64;
  int tid = threadIdx.x;
  const float* Sb  = S  + (size_t)b * LC_ * SP;
  const float* Qtb = Qt + (size_t)b * LQ_ * D_;
  const float* Mb  = M  + (size_t)b * JP * D_;

  for(int idx=tid; idx<64*26; idx+=256){
    int il = idx / 26, f = idx % 26;
    int i = i0 + il;
    float4 v = make_float4(0.f,0.f,0.f,0.f);
    if(i < LC_ && f < 25) v = *(const float4*)&Sb[(size_t)i*SP + f*4];
    *(float4*)&S1s[il*104 + f*4] = v;
  }
  __syncthreads();

  {
    int w = tid >> 6, l = tid & 63;
    for(int r=0; r<16; r++){
      int il = w*16 + r;
      float x0 = (2*l   < LQ_) ? S1s[il*104 + 2*l  ] : -1e30f;
      float x1 = (2*l+1 < LQ_) ? S1s[il*104 + 2*l+1] : -1e30f;
      float m = fmaxf(x0,x1);
#pragma unroll
      for(int mm=32;mm>0;mm>>=1) m = fmaxf(m, __shfl_xor(m, mm, 64));
      float e0 = (2*l   < LQ_) ? __expf(x0-m) : 0.f;
      float e1 = (2*l+1 < LQ_) ? __expf(x1-m) : 0.f;
      float s = e0+e1;
#pragma unroll
      for(int mm=32;mm>0;mm>>=1) s += __shfl_xor(s, mm, 64);
      float inv = 1.f/s;
      if(2*l   < LQ_) S1s[il*104 + 2*l  ] = e0*inv;
      if(2*l+1 < LQ_) S1s[il*104 + 2*l+1] = e1*inv;
    }
  }

  int dt = tid & 31;
  int it = tid >> 5;
  float A[8][4] = {}, Bm[8][4] = {};
  for(int j0=0; j0<LQ_; j0+=16){
    int nj = min(16, LQ_-j0);
    __syncthreads();
    for(int idx=tid; idx<nj*32; idx+=256){
      int jj = idx >> 5, f = idx & 31;
      *(float4*)&Qc[jj*132 + f*4] = *(const float4*)&Qtb[(size_t)(j0+jj)*D_ + f*4];
      *(float4*)&Mc[jj*132 + f*4] = *(const float4*)&Mb [(size_t)(j0+jj)*D_ + f*4];
    }
    __syncthreads();
    for(int jj4=0; jj4<nj; jj4+=4){
      float4 sv[8], qv[4], mv[4];
#pragma unroll
      for(int ii=0; ii<8; ii++) sv[ii] = *(const float4*)&S1s[(it*8+ii)*104 + j0+jj4];
#pragma unroll
      for(int jj=0; jj<4; jj++){
        qv[jj] = *(const float4*)&Qc[(jj4+jj)*132 + dt*4];
        mv[jj] = *(const float4*)&Mc[(jj4+jj)*132 + dt*4];
      }
#pragma unroll
      for(int ii=0; ii<8; ii++){
        float sf[4] = {sv[ii].x, sv[ii].y, sv[ii].z, sv[ii].w};
#pragma unroll
        for(int jj=0; jj<4; jj++){
          A[ii][0]  += sf[jj]*qv[jj].x; A[ii][1]  += sf[jj]*qv[jj].y;
          A[ii][2]  += sf[jj]*qv[jj].z; A[ii][3]  += sf[jj]*qv[jj].w;
          Bm[ii][0] += sf[jj]*mv[jj].x; Bm[ii][1] += sf[jj]*mv[jj].y;
          Bm[ii][2] += sf[jj]*mv[jj].z; Bm[ii][3] += sf[jj]*mv[jj].w;
        }
      }
    }
  }

  const float* Cb = C + (size_t)b * D_ * LC_;
  float* ob = out + (size_t)b * 512 * LC_;
  int il2 = tid & 63, dg = tid >> 6;
  int i = i0 + il2;

  __syncthreads();
#pragma unroll
  for(int ii=0; ii<8; ii++)
#pragma unroll
    for(int dd=0; dd<4; dd++) At[(it*8+ii)*133 + dt*4+dd] = A[ii][dd];
  __syncthreads();
  if(i < LC_){
    for(int dd2=0; dd2<32; dd2++){
      int d = dg*32 + dd2;
      float a = At[il2*133 + d];
      float c = Cb[(size_t)d*LC_ + i];
      ob[(size_t)d*LC_ + i]       = c;
      ob[(size_t)(128+d)*LC_ + i] = a;
      ob[(size_t)(256+d)*LC_ + i] = c*a;
    }
  }
  __syncthreads();
#pragma unroll
  for(int ii=0; ii<8; ii++)
#pragma unroll
    for(int dd=0; dd<4; dd++) At[(it*8+ii)*133 + dt*4+dd] = Bm[ii][dd];
  __syncthreads();
  if(i < LC_){
    for(int dd2=0; dd2<32; dd2++){
      int d = dg*32 + dd2;
      float bm = At[il2*133 + d];
      float c  = Cb[(size_t)d*LC_ + i];
      ob[(size_t)(384+d)*LC_ + i] = c*bm;
    }
  }
}

extern "C" void kernel_launch(void* const* d_in, const int* in_sizes, int n_in,
                              void* d_out, int out_size, void* d_ws, size_t ws_size,
                              hipStream_t stream){
  const float* C = (const float*)d_in[0];
  const float* Q = (const float*)d_in[1];
  const float* W = (const float*)d_in[2];
  float* out = (float*)d_out;
  float* ws  = (float*)d_ws;
  // ws layout (floats): S 6.656M | Ct 8.192M | M 1.049M | Qt 0.819M | pm/ps 65.5K*2 | cm/cs 8.2K*2 = 67.5 MB
  float* S  = ws;
  float* Ct = ws + 6656000;
  float* M  = ws + 14848000;
  float* Qt = ws + 15896576;
  float* pm = ws + 16715776;
  float* ps = ws + 16781312;
  float* cm = ws + 16846848;
  float* cs = ws + 16855040;

  k_transpose <<<dim3(32,4,64), dim3(32,8), 0, stream>>>(C, Ct);
  k_transposeQ<<<dim3(4,4,64),  dim3(32,8), 0, stream>>>(Q, Qt);
  k_S         <<<dim3(16,64),   256, 0, stream>>>(Q, W, Ct, S);
  k_colstats1 <<<dim3(64,NIC),  256, 0, stream>>>(S, pm, ps);
  k_colstats2 <<<64,            128, 0, stream>>>(pm, ps, cm, cs);
  k_Mj        <<<dim3(64,4),    1024, 0, stream>>>(S, Ct, cm, cs, M);
  k_final     <<<dim3(16,64),   256, 0, stream>>>(S, Qt, M, C, out);
}